// Round 1
// baseline (751.428 us; speedup 1.0000x reference)
//
#include <hip/hip_runtime.h>
#include <hip/hip_bf16.h>

// ConvTransE decoder, fused bf16-MFMA implementation.
//
//   scores[b] = sum_d ( sum_{f,p} relu(conv[b,f,p]) * fc[f*1022+p][d] + fc_bias[d] ) * obj_e[b][d]
//
// Strategy: one big bf16 GEMM (M=8192, N=512, K=32704) with the A operand
// (relu'd conv output) generated on the fly into LDS, B = fc transposed+
// K-reordered (k' = p*32+f) into ws as bf16, epilogue fused obj-dot with
// atomicAdd into d_out. Split-K=2 to reach 512 blocks (2 blocks/CU).
// ws layout: [0,32MiB) combined f32 (8192x1024); [32MiB, 64MiB) fcT bf16 (512x32704).

#define ND    512
#define NF    32
#define NP    1022
#define KTOT  32704      // NP*NF
#define NB    8192
#define BM    128
#define BN    128
#define BK    64
#define NSTEPS 511       // KTOT/BK

typedef __attribute__((ext_vector_type(8))) short bf16x8;
typedef __attribute__((ext_vector_type(4))) float f32x4;

typedef const __attribute__((address_space(1))) unsigned int* gas1_p;
typedef __attribute__((address_space(3))) unsigned int* las3_p;

__device__ __forceinline__ void gload_lds16(const void* g, const void* l) {
  // global -> LDS direct, 16B per lane. LDS dest is wave-uniform base + lane*16.
  __builtin_amdgcn_global_load_lds((gas1_p)(unsigned long long)(uintptr_t)g,
                                   (las3_p)(unsigned int)(uintptr_t)l, 16, 0, 0);
}

__device__ __forceinline__ unsigned int pack_bf16x2(float a, float b) {
  __hip_bfloat162 hh = __float22bfloat162_rn(make_float2(a, b));
  unsigned int u;
  __builtin_memcpy(&u, &hh, 4);
  return u;
}

// ---------------- K1: gather combined = [subj_e | rel_e] ----------------
__global__ __launch_bounds__(256) void k_gather(const float* __restrict__ ent,
                                                const float* __restrict__ rel,
                                                const int* __restrict__ trip,
                                                float* __restrict__ comb) {
  int b = blockIdx.x, t = threadIdx.x;
  int s = trip[b * 3 + 0], r = trip[b * 3 + 1];
  float4 v;
  if (t < 128) v = ((const float4*)(ent + (size_t)s * ND))[t];
  else         v = ((const float4*)(rel + (size_t)r * ND))[t - 128];
  ((float4*)(comb + (size_t)b * 1024))[t] = v;
}

// ---------------- K2: fcT[d][p*32+f] = (bf16) fc[f*1022+p][d] ----------------
__global__ __launch_bounds__(256) void k_fcT(const float* __restrict__ fc,
                                             unsigned short* __restrict__ fcT) {
  __shared__ float tile[32][132];   // [f][d-local], padded (132%32=4) for column reads
  int p = blockIdx.x >> 2, dt = blockIdx.x & 3;
  int d0 = dt * 128, t = threadIdx.x;
  int f = t >> 3, l8 = t & 7;
  const float* src = fc + ((size_t)f * NP + p) * ND + d0 + l8 * 16;
#pragma unroll
  for (int j = 0; j < 4; ++j) {
    float4 v = *(const float4*)(src + j * 4);
    *(float4*)&tile[f][l8 * 16 + j * 4] = v;
  }
  __syncthreads();
  if (t < 128) {
    unsigned int outw[16];
#pragma unroll
    for (int fq = 0; fq < 16; ++fq)
      outw[fq] = pack_bf16x2(tile[2 * fq][t], tile[2 * fq + 1][t]);
    unsigned short* dst = fcT + (size_t)(d0 + t) * KTOT + p * NF;  // 64B aligned
#pragma unroll
    for (int i = 0; i < 4; ++i) {
      uint4 w;
      w.x = outw[i * 4 + 0]; w.y = outw[i * 4 + 1];
      w.z = outw[i * 4 + 2]; w.w = outw[i * 4 + 3];
      *(uint4*)((char*)dst + i * 16) = w;
    }
  }
}

// ---------------- K3: fused GEMM + obj-dot epilogue ----------------
// grid = 512: bid&7 -> xcd; n_blk = xcd>>1 (4 cols), ksp = xcd&1 (split-K 2),
// m_blk = bid>>3 (64). 4 waves (2x2), wave tile 64x64, acc 4x4 frags.
__global__ __launch_bounds__(256, 2) void k_gemm(
    const float* __restrict__ comb, const unsigned short* __restrict__ fcT,
    const float* __restrict__ cw, const float* __restrict__ cb,
    const float* __restrict__ fcb, const int* __restrict__ trip,
    const float* __restrict__ ent, float* __restrict__ out) {
  __shared__ unsigned short Al[BM * BK];   // swizzled: row m, slot ^= (m&7)
  __shared__ unsigned short Bl[BN * BK];   // swizzled via pre-swizzled global src
  __shared__ float wk[3 * 32];
  __shared__ float wb[32];

  const int tid = threadIdx.x;
  const int bid = blockIdx.x;
  const int xcd = bid & 7;
  const int n_blk = xcd >> 1, ksp = xcd & 1, m_blk = bid >> 3;

  if (tid < 96) wk[(tid % 3) * 32 + (tid / 3)] = cw[tid];  // wk[k*32+f] = cw[f*3+k]
  if (tid < 32) wb[tid] = cb[tid];

  const int m_local = tid >> 1;        // 0..127: A row this thread generates
  const int h = tid & 1;               // which 32-wide k-half (conv position)
  const float* crow = comb + (size_t)(m_blk * BM + m_local) * 1024;

  const int wv = tid >> 6, lane = tid & 63;
  const int wm = wv >> 1, wn = wv & 1;
  const int r16 = lane & 15, rq = lane >> 4;

  f32x4 acc[4][4];
#pragma unroll
  for (int i = 0; i < 4; ++i)
#pragma unroll
    for (int j = 0; j < 4; ++j)
      acc[i][j] = (f32x4)0.0f;

  const int s_begin = ksp ? 256 : 0;
  const int s_end   = ksp ? NSTEPS : 256;

  __syncthreads();

  // conv inputs for first step (p0 = 2*s): need combined[p0..p0+3]
  float2 c01 = *(const float2*)(crow + 2 * s_begin);
  float2 c23 = *(const float2*)(crow + 2 * s_begin + 2);

  for (int s = s_begin; s < s_end; ++s) {
    const int k0 = s * BK;

    // ---- stage B: 16KB via global_load_lds, source pre-swizzled so linear
    // LDS dest lands XOR-swizzled (slot ^= d&7). 4 rounds x 256 lanes x 16B.
#pragma unroll
    for (int r = 0; r < 4; ++r) {
      int c = r * 256 + tid;
      int dl = c >> 3, kq = c & 7;
      int kqs = kq ^ (dl & 7);
      const unsigned short* src =
          fcT + (size_t)(n_blk * BN + dl) * KTOT + (k0 + kqs * 8);
      gload_lds16(src, Bl + (size_t)(r * 256 + wv * 64) * 8);
    }

    // ---- generate A tile: 32 filters at position p0+h, row m_local
    float ca, cbv, ccv;
    if (h == 0) { ca = c01.x; cbv = c01.y; ccv = c23.x; }
    else        { ca = c01.y; cbv = c23.x; ccv = c23.y; }
    unsigned int pk[16];
#pragma unroll
    for (int fq = 0; fq < 16; ++fq) {
      int f0 = 2 * fq, f1 = 2 * fq + 1;
      float v0 = fmaxf(0.f, wb[f0] + wk[f0] * ca + wk[32 + f0] * cbv + wk[64 + f0] * ccv);
      float v1 = fmaxf(0.f, wb[f1] + wk[f1] * ca + wk[32 + f1] * cbv + wk[64 + f1] * ccv);
      pk[fq] = pack_bf16x2(v0, v1);
    }
#pragma unroll
    for (int i = 0; i < 4; ++i) {
      int slot = (h * 4 + i) ^ (m_local & 7);
      uint4 w;
      w.x = pk[i * 4 + 0]; w.y = pk[i * 4 + 1];
      w.z = pk[i * 4 + 2]; w.w = pk[i * 4 + 3];
      *(uint4*)((char*)Al + m_local * 128 + slot * 16) = w;
    }

    // prefetch next step's conv inputs (latency hides under MFMA phase)
    if (s + 1 < s_end) {
      c01 = *(const float2*)(crow + 2 * (s + 1));
      c23 = *(const float2*)(crow + 2 * (s + 1) + 2);
    }

    __syncthreads();   // drains vmcnt (B landed) + lgkm (A written)

    // ---- fragment reads (swizzled) + MFMA
    bf16x8 af[4][2], bfr[4][2];
#pragma unroll
    for (int mi = 0; mi < 4; ++mi) {
      int row = wm * 64 + mi * 16 + r16;
#pragma unroll
      for (int ks = 0; ks < 2; ++ks) {
        int slot = (ks * 4 + rq) ^ (row & 7);
        af[mi][ks] = *(const bf16x8*)((const char*)Al + row * 128 + slot * 16);
      }
    }
#pragma unroll
    for (int ni = 0; ni < 4; ++ni) {
      int dl = wn * 64 + ni * 16 + r16;
#pragma unroll
      for (int ks = 0; ks < 2; ++ks) {
        int slot = (ks * 4 + rq) ^ (dl & 7);
        bfr[ni][ks] = *(const bf16x8*)((const char*)Bl + dl * 128 + slot * 16);
      }
    }
#pragma unroll
    for (int ks = 0; ks < 2; ++ks)
#pragma unroll
      for (int mi = 0; mi < 4; ++mi)
#pragma unroll
        for (int ni = 0; ni < 4; ++ni)
          acc[mi][ni] = __builtin_amdgcn_mfma_f32_16x16x32_bf16(
              af[mi][ks], bfr[ni][ks], acc[mi][ni], 0, 0, 0);

    __syncthreads();   // protect LDS from next iteration's staging
  }

  // ---- epilogue: scores[b] += sum_d (proj + fc_bias) * obj_e[b][d]
  // C/D layout (m89-verified): col = lane&15, row = (lane>>4)*4 + reg.
  const int colbase = n_blk * BN + wn * 64;
#pragma unroll
  for (int mi = 0; mi < 4; ++mi) {
#pragma unroll
    for (int rr = 0; rr < 4; ++rr) {
      int row = m_blk * BM + wm * 64 + mi * 16 + rq * 4 + rr;
      int oid = trip[row * 3 + 2];
      const float* orow = ent + (size_t)oid * ND + colbase;
      float part = 0.f;
#pragma unroll
      for (int ni = 0; ni < 4; ++ni) {
        int d = ni * 16 + r16;
        float v = acc[mi][ni][rr];
        if (ksp == 0) v += fcb[colbase + d];   // add bias exactly once per (b,d)
        part += v * orow[d];
      }
      part += __shfl_xor(part, 1);
      part += __shfl_xor(part, 2);
      part += __shfl_xor(part, 4);
      part += __shfl_xor(part, 8);
      if (r16 == 0) atomicAdd(out + row, part);
    }
  }
}

extern "C" void kernel_launch(void* const* d_in, const int* in_sizes, int n_in,
                              void* d_out, int out_size, void* d_ws, size_t ws_size,
                              hipStream_t stream) {
  const float* ent = (const float*)d_in[0];
  const float* rel = (const float*)d_in[1];
  const float* cw  = (const float*)d_in[2];
  const float* cb  = (const float*)d_in[3];
  const float* fc  = (const float*)d_in[4];
  const float* fcb = (const float*)d_in[5];
  const int*   trp = (const int*)d_in[6];
  float* out = (float*)d_out;

  float* comb = (float*)d_ws;                                        // 33.5 MB
  unsigned short* fcT = (unsigned short*)((char*)d_ws + (size_t)NB * 1024 * 4);  // 33.5 MB

  hipMemsetAsync(d_out, 0, (size_t)out_size * sizeof(float), stream);
  k_gather<<<NB, 256, 0, stream>>>(ent, rel, trp, comb);
  k_fcT<<<NP * 4, 256, 0, stream>>>(fc, fcT);
  k_gemm<<<512, 256, 0, stream>>>(comb, fcT, cw, cb, fcb, trp, ent, out);
}

// Round 2
// 612.296 us; speedup vs baseline: 1.2272x; 1.2272x over previous
//
#include <hip/hip_runtime.h>
#include <hip/hip_bf16.h>

// ConvTransE decoder, fused bf16-MFMA implementation, round 2.
//
//   scores[b] = sum_d ( sum_{f,p} relu(conv[b,f,p]) * fc[f*1022+p][d] + fc_bias[d] ) * obj_e[b][d]
//
// R2 changes vs R1 (R1: 517us gemm, MfmaUtil 23%, VALUBusy 40%):
//  - BN 128->256: A-tile regenerated per n-block; 2 n-blocks instead of 4
//    halves total A-gen VALU (VALU was out-consuming the matrix pipe).
//  - 512 threads / 8 waves (2x4 wave grid, wave tile 64x64): per-thread
//    A-gen halves again (16 elems), 4 waves/SIMD for MFMA||VALU overlap.
//  - split-K=4 keeps grid at 512 = 2 blocks/CU; xcd = n_blk*4+ksp so each
//    XCD's B panel (256 x 8176 bf16 = 4.2 MB) ~fits its private L2.
// ws layout: [0,32MiB) combined f32 (8192x1024); [32MiB,64MiB) fcT bf16 (512x32704).

#define ND    512
#define NF    32
#define NP    1022
#define KTOT  32704      // NP*NF
#define NB    8192
#define BM    128
#define BN    256
#define BK    64
#define NSTEPS 511       // KTOT/BK

typedef __attribute__((ext_vector_type(8))) short bf16x8;
typedef __attribute__((ext_vector_type(4))) float f32x4;

typedef const __attribute__((address_space(1))) unsigned int* gas1_p;
typedef __attribute__((address_space(3))) unsigned int* las3_p;

__device__ __forceinline__ void gload_lds16(const void* g, const void* l) {
  // global -> LDS direct, 16B per lane. LDS dest is wave-uniform base + lane*16.
  __builtin_amdgcn_global_load_lds((gas1_p)(unsigned long long)(uintptr_t)g,
                                   (las3_p)(unsigned int)(uintptr_t)l, 16, 0, 0);
}

__device__ __forceinline__ unsigned int pack_bf16x2(float a, float b) {
  __hip_bfloat162 hh = __float22bfloat162_rn(make_float2(a, b));
  unsigned int u;
  __builtin_memcpy(&u, &hh, 4);
  return u;
}

// ---------------- K1: gather combined = [subj_e | rel_e] ----------------
__global__ __launch_bounds__(256) void k_gather(const float* __restrict__ ent,
                                                const float* __restrict__ rel,
                                                const int* __restrict__ trip,
                                                float* __restrict__ comb) {
  int b = blockIdx.x, t = threadIdx.x;
  int s = trip[b * 3 + 0], r = trip[b * 3 + 1];
  float4 v;
  if (t < 128) v = ((const float4*)(ent + (size_t)s * ND))[t];
  else         v = ((const float4*)(rel + (size_t)r * ND))[t - 128];
  ((float4*)(comb + (size_t)b * 1024))[t] = v;
}

// ---------------- K2: fcT[d][p*32+f] = (bf16) fc[f*1022+p][d] ----------------
__global__ __launch_bounds__(256) void k_fcT(const float* __restrict__ fc,
                                             unsigned short* __restrict__ fcT) {
  __shared__ float tile[32][132];   // [f][d-local], padded (132%32=4) for column reads
  int p = blockIdx.x >> 2, dt = blockIdx.x & 3;
  int d0 = dt * 128, t = threadIdx.x;
  int f = t >> 3, l8 = t & 7;
  const float* src = fc + ((size_t)f * NP + p) * ND + d0 + l8 * 16;
#pragma unroll
  for (int j = 0; j < 4; ++j) {
    float4 v = *(const float4*)(src + j * 4);
    *(float4*)&tile[f][l8 * 16 + j * 4] = v;
  }
  __syncthreads();
  if (t < 128) {
    unsigned int outw[16];
#pragma unroll
    for (int fq = 0; fq < 16; ++fq)
      outw[fq] = pack_bf16x2(tile[2 * fq][t], tile[2 * fq + 1][t]);
    unsigned short* dst = fcT + (size_t)(d0 + t) * KTOT + p * NF;  // 64B aligned
#pragma unroll
    for (int i = 0; i < 4; ++i) {
      uint4 w;
      w.x = outw[i * 4 + 0]; w.y = outw[i * 4 + 1];
      w.z = outw[i * 4 + 2]; w.w = outw[i * 4 + 3];
      *(uint4*)((char*)dst + i * 16) = w;
    }
  }
}

// ---------------- K3: fused GEMM + obj-dot epilogue ----------------
// grid = 512: xcd = bid&7 = n_blk*4 + ksp; m_blk = bid>>3 (64).
// 8 waves (2x4), wave tile 64x64, acc 4x4 frags, split-K=4.
__global__ __launch_bounds__(512, 4) void k_gemm(
    const float* __restrict__ comb, const unsigned short* __restrict__ fcT,
    const float* __restrict__ cw, const float* __restrict__ cb,
    const float* __restrict__ fcb, const int* __restrict__ trip,
    const float* __restrict__ ent, float* __restrict__ out) {
  __shared__ unsigned short Al[BM * BK];   // 16 KB, swizzled: row m, slot ^= (m&7)
  __shared__ unsigned short Bl[BN * BK];   // 32 KB, swizzled via pre-swizzled global src
  __shared__ float wk[3 * 32];
  __shared__ float wb[32];

  const int tid = threadIdx.x;
  const int bid = blockIdx.x;
  const int xcd = bid & 7;
  const int n_blk = xcd >> 2, ksp = xcd & 3, m_blk = bid >> 3;

  if (tid < 96) wk[(tid % 3) * 32 + (tid / 3)] = cw[tid];  // wk[k*32+f] = cw[f*3+k]
  if (tid < 32) wb[tid] = cb[tid];

  // A-gen mapping: each thread generates 16 elements of the 128x64 A tile.
  const int m_local = tid >> 2;        // 0..127: A row
  const int sub = tid & 3;
  const int h = sub >> 1;              // conv position half (0/1)
  const int fh = sub & 1;              // filter half (f 0..15 / 16..31)
  const float* crow = comb + (size_t)(m_blk * BM + m_local) * 1024;

  const int wv = tid >> 6, lane = tid & 63;
  const int wm = wv >> 2, wn = wv & 3;          // 2 x 4 wave grid
  const int r16 = lane & 15, rq = lane >> 4;

  f32x4 acc[4][4];
#pragma unroll
  for (int i = 0; i < 4; ++i)
#pragma unroll
    for (int j = 0; j < 4; ++j)
      acc[i][j] = (f32x4)0.0f;

  const int s_begin = (NSTEPS * ksp) >> 2;      // {0,127,255,383}
  const int s_end   = (NSTEPS * (ksp + 1)) >> 2;

  __syncthreads();

  // conv inputs for first step (p0 = 2*s): need combined[p0..p0+3]
  float2 c01 = *(const float2*)(crow + 2 * s_begin);
  float2 c23 = *(const float2*)(crow + 2 * s_begin + 2);

  for (int s = s_begin; s < s_end; ++s) {
    const int k0 = s * BK;

    // ---- stage B: 32KB via global_load_lds, source pre-swizzled so linear
    // LDS dest lands XOR-swizzled (slot ^= d&7). 4 rounds x 512 lanes x 16B.
#pragma unroll
    for (int r = 0; r < 4; ++r) {
      int c = r * 512 + tid;
      int dl = c >> 3, kq = c & 7;
      int kqs = kq ^ (dl & 7);
      const unsigned short* src =
          fcT + (size_t)(n_blk * BN + dl) * KTOT + (k0 + kqs * 8);
      gload_lds16(src, Bl + (size_t)(r * 512 + wv * 64) * 8);
    }

    // ---- generate A tile slice: 16 filter-values at position 2s+h
    float ca, cbv, ccv;
    if (h == 0) { ca = c01.x; cbv = c01.y; ccv = c23.x; }
    else        { ca = c01.y; cbv = c23.x; ccv = c23.y; }
    unsigned int pk[8];
#pragma unroll
    for (int j = 0; j < 8; ++j) {
      int f0 = fh * 16 + 2 * j, f1 = f0 + 1;
      float v0 = fmaxf(0.f, wb[f0] + wk[f0] * ca + wk[32 + f0] * cbv + wk[64 + f0] * ccv);
      float v1 = fmaxf(0.f, wb[f1] + wk[f1] * ca + wk[32 + f1] * cbv + wk[64 + f1] * ccv);
      pk[j] = pack_bf16x2(v0, v1);
    }
#pragma unroll
    for (int i = 0; i < 2; ++i) {
      int slot = (h * 4 + fh * 2 + i) ^ (m_local & 7);
      uint4 w;
      w.x = pk[i * 4 + 0]; w.y = pk[i * 4 + 1];
      w.z = pk[i * 4 + 2]; w.w = pk[i * 4 + 3];
      *(uint4*)((char*)Al + m_local * 128 + slot * 16) = w;
    }

    // prefetch next step's conv inputs (latency hides under MFMA phase)
    if (s + 1 < s_end) {
      c01 = *(const float2*)(crow + 2 * (s + 1));
      c23 = *(const float2*)(crow + 2 * (s + 1) + 2);
    }

    __syncthreads();   // drains vmcnt (B landed) + lgkm (A written)

    // ---- fragment reads (swizzled) + MFMA
    bf16x8 af[4][2], bfr[4][2];
#pragma unroll
    for (int mi = 0; mi < 4; ++mi) {
      int row = wm * 64 + mi * 16 + r16;
#pragma unroll
      for (int ks = 0; ks < 2; ++ks) {
        int slot = (ks * 4 + rq) ^ (row & 7);
        af[mi][ks] = *(const bf16x8*)((const char*)Al + row * 128 + slot * 16);
      }
    }
#pragma unroll
    for (int ni = 0; ni < 4; ++ni) {
      int dl = wn * 64 + ni * 16 + r16;
#pragma unroll
      for (int ks = 0; ks < 2; ++ks) {
        int slot = (ks * 4 + rq) ^ (dl & 7);
        bfr[ni][ks] = *(const bf16x8*)((const char*)Bl + dl * 128 + slot * 16);
      }
    }
#pragma unroll
    for (int ks = 0; ks < 2; ++ks)
#pragma unroll
      for (int mi = 0; mi < 4; ++mi)
#pragma unroll
        for (int ni = 0; ni < 4; ++ni)
          acc[mi][ni] = __builtin_amdgcn_mfma_f32_16x16x32_bf16(
              af[mi][ks], bfr[ni][ks], acc[mi][ni], 0, 0, 0);

    __syncthreads();   // protect LDS from next iteration's staging
  }

  // ---- epilogue: scores[b] += sum_d (proj + fc_bias) * obj_e[b][d]
  // C/D layout (m89-verified): col = lane&15, row = (lane>>4)*4 + reg.
  const int colbase = n_blk * BN + wn * 64;
#pragma unroll
  for (int mi = 0; mi < 4; ++mi) {
#pragma unroll
    for (int rr = 0; rr < 4; ++rr) {
      int row = m_blk * BM + wm * 64 + mi * 16 + rq * 4 + rr;
      int oid = trip[row * 3 + 2];
      const float* orow = ent + (size_t)oid * ND + colbase;
      float part = 0.f;
#pragma unroll
      for (int ni = 0; ni < 4; ++ni) {
        int d = ni * 16 + r16;
        float v = acc[mi][ni][rr];
        if (ksp == 0) v += fcb[colbase + d];   // add bias exactly once per (b,d)
        part += v * orow[d];
      }
      part += __shfl_xor(part, 1);
      part += __shfl_xor(part, 2);
      part += __shfl_xor(part, 4);
      part += __shfl_xor(part, 8);
      if (r16 == 0) atomicAdd(out + row, part);
    }
  }
}

extern "C" void kernel_launch(void* const* d_in, const int* in_sizes, int n_in,
                              void* d_out, int out_size, void* d_ws, size_t ws_size,
                              hipStream_t stream) {
  const float* ent = (const float*)d_in[0];
  const float* rel = (const float*)d_in[1];
  const float* cw  = (const float*)d_in[2];
  const float* cb  = (const float*)d_in[3];
  const float* fc  = (const float*)d_in[4];
  const float* fcb = (const float*)d_in[5];
  const int*   trp = (const int*)d_in[6];
  float* out = (float*)d_out;

  float* comb = (float*)d_ws;                                        // 33.5 MB
  unsigned short* fcT = (unsigned short*)((char*)d_ws + (size_t)NB * 1024 * 4);  // 33.5 MB

  hipMemsetAsync(d_out, 0, (size_t)out_size * sizeof(float), stream);
  k_gather<<<NB, 256, 0, stream>>>(ent, rel, trp, comb);
  k_fcT<<<NP * 4, 256, 0, stream>>>(fc, fcT);
  k_gemm<<<512, 512, 0, stream>>>(comb, fcT, cw, cb, fcb, trp, ent, out);
}